// Round 5
// baseline (386.725 us; speedup 1.0000x reference)
//
#include <hip/hip_runtime.h>

#define M 2048
#define N 131072
#define D 256

#define SLICE_G 64                     // 16-row tiles per slice (1024 n per slice)
#define NSLICE  (N / (SLICE_G * 16))   // 128
#define GEN     8                      // tiles per generation (barrier cadence)
#define NGEN    (SLICE_G / GEN)        // 8
#define NQBLK   4                      // 4 q-blocks x 512 rows
#define BIAS    1024.0f                // score = vsq+BIAS-2qv > 0 -> uint-sortable bits

typedef __attribute__((ext_vector_type(8))) _Float16 half8;  // 8 f16 (4 VGPRs)
typedef __attribute__((ext_vector_type(8))) short short8;
typedef __attribute__((ext_vector_type(4))) float f32x4;     // MFMA acc
typedef unsigned long long ull;

__device__ __forceinline__ ull pack_key(float score, unsigned idx) {
    unsigned u = __float_as_uint(score);
    u = (u & 0x80000000u) ? ~u : (u | 0x80000000u);
    return ((ull)u << 32) | idx;
}

// ---------------- Kernel B: FUSED, generation-pipelined ----------------
// R4 failed on (a) deterministic scratch spill (WRITE 75MB exact) and (b) per-tile
// barrier lockstep (MfmaUtil 22%). This version:
//  * 512-thread blocks: 8 waves x 64 q-rows; each wave stages ONE chunk/tile (8 regs).
//    Budget: aq 128 (AGPR) + acc 16 + best 16 + stage 8 + temps ~30 = ~200 <= 256
//    at __launch_bounds__(512,2) -> no spill.
//  * LDS = 2 generations x 8 tiles x 8KB f16 frag-linear (128KB) + 8KB vsq partials.
//    ONE barrier per 8-tile generation (~10k cyc apart); within a gen, waves free-run:
//    per tile {issue next-gen loads -> 32 MFMA + keymin -> cvt + ds_write next-gen}.
//    Load cover = one compute phase (~700cyc) > L2 latency (slice stays XCD-L2-hot).
//  * All LDS access 16B/lane linear (R1/R3/R4-measured 0 bank conflicts).
__global__ __launch_bounds__(512, 2) void dist_argmin_fused(const float* __restrict__ q,
                                                            const float* __restrict__ v,
                                                            ull* __restrict__ keys1,
                                                            ull* __restrict__ keys2) {
    __shared__ short bt[2][GEN][8 * 512];     // 128 KB: [gen-buf][tile][chunk*512+lane*8]
    __shared__ float vsq_s[2][GEN][16][8];    // 8 KB:   [gen-buf][tile][tx][wave]

    const int tid  = threadIdx.x;
    const int lane = tid & 63;
    const int w    = tid >> 6;               // 0..7: wave id == chunk this wave stages
    const int tx   = lane & 15;
    const int quad = (lane >> 4) & 3;

    // XCD swizzle: 512 blocks; lb%8 = XCD; consecutive s_ = same slice's 4 qblks
    const int lb    = blockIdx.x;
    const int xcd   = lb & 7;
    const int s_    = lb >> 3;               // 0..63 within XCD
    const int slice = xcd * 16 + (s_ >> 2);
    const int qblk  = s_ & 3;

    const int qb0 = qblk * 512 + w * 64;     // wave's first q-row (64 rows)
    const int sg0 = slice * SLICE_G;

    // Prologue: A-frags direct from fp32 q (LLC-resident), cvt in regs (128 regs)
    half8 aq[4][8];
#pragma unroll
    for (int mt = 0; mt < 4; ++mt) {
        const float* qrow = q + (size_t)(qb0 + mt * 16 + tx) * 256 + quad * 8;
#pragma unroll
        for (int c = 0; c < 8; ++c) {
            const float4 f0 = *(const float4*)(qrow + c * 32);
            const float4 f1 = *(const float4*)(qrow + c * 32 + 4);
            half8 hh;
            hh[0] = (_Float16)f0.x; hh[1] = (_Float16)f0.y;
            hh[2] = (_Float16)f0.z; hh[3] = (_Float16)f0.w;
            hh[4] = (_Float16)f1.x; hh[5] = (_Float16)f1.y;
            hh[6] = (_Float16)f1.z; hh[7] = (_Float16)f1.w;
            aq[mt][c] = hh;
        }
    }

    unsigned best[16];
#pragma unroll
    for (int i = 0; i < 16; ++i) best[i] = 0xFFFFFFFFu;

    // wave's staging source: row tx of each tile, cols w*32 + quad*8 (..+7)
    const float* vp = v + ((size_t)sg0 * 16 + tx) * 256 + w * 32 + quad * 8;

    auto cvtwrite = [&](int buf, int t, const float4& f0, const float4& f1) {
        float s = f0.x * f0.x + f0.y * f0.y + f0.z * f0.z + f0.w * f0.w;
        s = fmaf(f1.x, f1.x, s); s = fmaf(f1.y, f1.y, s);
        s = fmaf(f1.z, f1.z, s); s = fmaf(f1.w, f1.w, s);
        half8 h;
        h[0] = (_Float16)f0.x; h[1] = (_Float16)f0.y;
        h[2] = (_Float16)f0.z; h[3] = (_Float16)f0.w;
        h[4] = (_Float16)f1.x; h[5] = (_Float16)f1.y;
        h[6] = (_Float16)f1.z; h[7] = (_Float16)f1.w;
        *(short8*)&bt[buf][t][w * 512 + lane * 8] = *(short8*)&h;   // 16B/lane linear
        s += __shfl_xor(s, 16, 64);
        s += __shfl_xor(s, 32, 64);          // full row-tx sumsq over this chunk's 32 k
        if (lane < 16) vsq_s[buf][t][lane][w] = s;
    };

    auto compute = [&](int buf, int t, int g) {
        const float4 p0 = *(const float4*)&vsq_s[buf][t][tx][0];
        const float4 p1 = *(const float4*)&vsq_s[buf][t][tx][4];
        const float vsqr = ((p0.x + p0.y) + (p0.z + p0.w))
                         + ((p1.x + p1.y) + (p1.z + p1.w)) + BIAS;
        f32x4 acc[4];
#pragma unroll
        for (int i = 0; i < 4; ++i) acc[i] = (f32x4){0.f, 0.f, 0.f, 0.f};
        __builtin_amdgcn_s_setprio(1);
#pragma unroll
        for (int c = 0; c < 8; ++c) {
            const half8 b = *(const half8*)&bt[buf][t][c * 512 + lane * 8];
#pragma unroll
            for (int mt = 0; mt < 4; ++mt)
                acc[mt] = __builtin_amdgcn_mfma_f32_16x16x32_f16(aq[mt][c], b, acc[mt], 0, 0, 0);
        }
        __builtin_amdgcn_s_setprio(0);
#pragma unroll
        for (int mt = 0; mt < 4; ++mt)
#pragma unroll
            for (int r = 0; r < 4; ++r) {
                const float sc = fmaf(-2.f, acc[mt][r], vsqr);
                const unsigned key = (__float_as_uint(sc) & 0xFFFFFFC0u) | (unsigned)g;
                const int sl = mt * 4 + r;
                best[sl] = key < best[sl] ? key : best[sl];
            }
    };

    // Fill generation 0 into buf 0 (2-deep pipelined loads)
    for (int t = 0; t < GEN; t += 2) {
        const float* p0 = vp + (size_t)t * 4096;
        const float* p1 = vp + (size_t)(t + 1) * 4096;
        const float4 a0 = *(const float4*)p0;
        const float4 a1 = *(const float4*)(p0 + 4);
        const float4 b0 = *(const float4*)p1;
        const float4 b1 = *(const float4*)(p1 + 4);
        cvtwrite(0, t, a0, a1);
        cvtwrite(0, t + 1, b0, b1);
    }
    __syncthreads();

    int buf = 0;
    for (int gen = 0; gen < NGEN; ++gen) {
        const int gbase = gen * GEN;
        if (gen + 1 < NGEN) {
            for (int t = 0; t < GEN; ++t) {
                const float* p = vp + (size_t)(gbase + GEN + t) * 4096;
                const float4 f0 = *(const float4*)p;          // issued before compute:
                const float4 f1 = *(const float4*)(p + 4);    // ~1 compute phase of cover
                compute(buf, t, gbase + t);
                cvtwrite(buf ^ 1, t, f0, f1);
            }
        } else {
            for (int t = 0; t < GEN; ++t) compute(buf, t, gbase + t);
        }
        __syncthreads();                     // one barrier per 8-tile generation
        buf ^= 1;
    }

    // Epilogue: per slot, min across 16 tx lanes; recover (g, tx); top-2 insert.
#pragma unroll
    for (int mt = 0; mt < 4; ++mt)
#pragma unroll
        for (int r = 0; r < 4; ++r) {
            const int sl = mt * 4 + r;
            unsigned k = best[sl];
#pragma unroll
            for (int off = 8; off; off >>= 1) {
                const unsigned o = (unsigned)__shfl_xor((int)k, off, 16);
                k = o < k ? o : k;
            }
            const ull bal = __ballot(best[sl] == k);
            const unsigned grp = (unsigned)((bal >> (quad * 16)) & 0xFFFFull);
            const int wtx = __ffs((int)grp) - 1;
            const unsigned n = (unsigned)((sg0 + (int)(k & 63u)) * 16 + wtx);
            if (tx == 0) {
                const int row = qb0 + mt * 16 + quad * 4 + r;
                const ull key64 = ((ull)k << 32) | n;
                const ull old = atomicMin(&keys1[row], key64);
                const ull loser = (key64 < old) ? old : key64;
                if (loser != ~0ull) atomicMin(&keys2[row], loser);
            }
        }
}

// ---------------- Kernel C: exact fp32 rescore of approx top-2 ----------------
__global__ __launch_bounds__(256) void rescore_kernel(const float* __restrict__ q,
                                                      const float* __restrict__ v,
                                                      const ull* __restrict__ keys1,
                                                      const ull* __restrict__ keys2,
                                                      int* __restrict__ out) {
    const int qi   = blockIdx.x * 4 + (threadIdx.x >> 6);
    const int lane = threadIdx.x & 63;
    const float4 qv = *(const float4*)(q + (size_t)qi * D + lane * 4);
    ull best = ~0ull;
    ull cand[2];
    cand[0] = keys1[qi];
    cand[1] = keys2[qi];
#pragma unroll
    for (int c = 0; c < 2; ++c) {
        if (cand[c] == ~0ull) continue;
        const unsigned idx = (unsigned)cand[c];
        const float4 vv = *(const float4*)(v + (size_t)idx * D + lane * 4);
        float s1 = vv.x * vv.x + vv.y * vv.y + vv.z * vv.z + vv.w * vv.w;   // ||v||^2
        float s2 = qv.x * vv.x + qv.y * vv.y + qv.z * vv.z + qv.w * vv.w;   // q.v
#pragma unroll
        for (int off = 32; off; off >>= 1) {
            s1 += __shfl_xor(s1, off, 64);
            s2 += __shfl_xor(s2, off, 64);
        }
        const float dist = fmaf(-2.0f, s2, s1);   // exact fp32 (sans ||q||^2)
        const ull key = pack_key(dist, idx);
        best = best < key ? best : key;
    }
    if (lane == 0) out[qi] = (int)(unsigned)(best & 0xFFFFFFFFull);
}

extern "C" void kernel_launch(void* const* d_in, const int* in_sizes, int n_in,
                              void* d_out, int out_size, void* d_ws, size_t ws_size,
                              hipStream_t stream) {
    const float* q = (const float*)d_in[0];
    const float* v = (const float*)d_in[1];
    int* out = (int*)d_out;

    ull* keys1 = (ull*)d_ws;                 // 32KB workspace total
    ull* keys2 = keys1 + M;

    hipMemsetAsync(d_ws, 0xFF, (size_t)2 * M * sizeof(ull), stream);

    dist_argmin_fused<<<NQBLK * NSLICE, 512, 0, stream>>>(q, v, keys1, keys2);

    rescore_kernel<<<M / 4, 256, 0, stream>>>(q, v, keys1, keys2, out);
}